// Round 1
// baseline (4716.491 us; speedup 1.0000x reference)
//
#include <hip/hip_runtime.h>

// ---------------- problem constants ----------------
#define NPTS   65536      // 16*4096
#define DIM    1024
#define NCODE  512
#define NLVL   3

// output layout (floats)
#define ZQ_OFF   0
#define LOSS_OFF 67108864
#define IDX_OFF  67108865
#define CB_OFF   67305473

// level-kernel tiling
#define BM  64            // points per block
#define NC  128           // code chunk
#define DK  32            // depth chunk
#define NTHR 256

// ---------------- helpers ----------------
__device__ inline void merge_top2(float& v1, int& i1, float& v2, int& i2,
                                  float w1, int j1, float w2, int j2) {
    // lexicographic (value, index) min — matches numpy argmin "first min" ties
    bool aFirst = (v1 < w1) || (v1 == w1 && i1 < j1);
    float t1v = aFirst ? v1 : w1; int t1i = aFirst ? i1 : j1;
    float c1v = aFirst ? v2 : w2; int c1i = aFirst ? i2 : j2;
    float c2v = aFirst ? w1 : v1; int c2i = aFirst ? j1 : i1;
    bool cFirst = (c1v < c2v) || (c1v == c2v && c1i < c2i);
    v1 = t1v; i1 = t1i;
    v2 = cFirst ? c1v : c2v;
    i2 = cFirst ? c1i : c2i;
}

// ---------------- codebook row norms (fp32, approx phase only) ----------------
__global__ __launch_bounds__(256) void cnorm_kernel(const float* __restrict__ cb,
                                                    float* __restrict__ cnorm) {
    __shared__ float sd[256];
    const int b = blockIdx.x;          // 0..1535  (l*512+k)
    const int tid = threadIdx.x;
    const float4 v = *(const float4*)&cb[(size_t)b * DIM + tid * 4];
    sd[tid] = v.x*v.x + v.y*v.y + v.z*v.z + v.w*v.w;
    __syncthreads();
    for (int o = 128; o > 0; o >>= 1) { if (tid < o) sd[tid] += sd[tid+o]; __syncthreads(); }
    if (tid == 0) cnorm[b] = sd[0];
}

// ---------------- per-level distance+argmin+residual kernel ----------------
// grid = NPTS/BM = 1024 blocks, 256 threads.
// r_out == nullptr for the last level (residual kept only in registers).
__global__ __launch_bounds__(256) void level_kernel(
        const float* __restrict__ r_in,      // [NPTS, DIM]
        float* __restrict__ r_out,           // [NPTS, DIM] or null
        const float* __restrict__ cb,        // [NCODE, DIM] this level
        const float* __restrict__ cnorm,     // [NCODE]
        float* __restrict__ out_idx_f,       // [NPTS] float indices (d_out slice)
        int*   __restrict__ ws_idx,          // [NPTS] int indices (ws)
        float* __restrict__ loss_partial)    // [1024] per-block loss partials
{
    __shared__ float A[DK][BM];        // residual tile, transposed [d][p]
    __shared__ float Bt[DK][NC];       // code tile, transposed [d][c]
    __shared__ int   s_i1[BM], s_i2[BM], s_w[BM];
    __shared__ double s_ref[BM][2][2];
    __shared__ float s_red[NTHR];

    const int tid = threadIdx.x;
    const int tx = tid & 15;           // code group (8 codes each)
    const int ty = tid >> 4;           // point group (4 points each)
    const int pbase = blockIdx.x * BM;

    float best1[4], best2[4]; int bi1[4], bi2[4];
    #pragma unroll
    for (int i = 0; i < 4; ++i) { best1[i] = 1e30f; best2[i] = 1e30f; bi1[i] = 0; bi2[i] = 1; }

    for (int cc = 0; cc < NCODE; cc += NC) {
        float acc[4][8];
        #pragma unroll
        for (int pi = 0; pi < 4; ++pi)
            #pragma unroll
            for (int ci = 0; ci < 8; ++ci) acc[pi][ci] = 0.0f;

        for (int ds = 0; ds < DIM; ds += DK) {
            __syncthreads();
            // stage A: 64 rows x 32 cols -> 512 float4, 2 per thread
            #pragma unroll
            for (int s = 0; s < 2; ++s) {
                int f = tid + s * 256;
                int row = f >> 3, c4 = f & 7;
                float4 v = *(const float4*)&r_in[(size_t)(pbase + row) * DIM + ds + c4 * 4];
                A[c4*4+0][row] = v.x; A[c4*4+1][row] = v.y;
                A[c4*4+2][row] = v.z; A[c4*4+3][row] = v.w;
            }
            // stage B: 128 rows x 32 cols -> 1024 float4, 4 per thread
            #pragma unroll
            for (int s = 0; s < 4; ++s) {
                int f = tid + s * 256;
                int row = f >> 3, c4 = f & 7;
                float4 v = *(const float4*)&cb[(size_t)(cc + row) * DIM + ds + c4 * 4];
                Bt[c4*4+0][row] = v.x; Bt[c4*4+1][row] = v.y;
                Bt[c4*4+2][row] = v.z; Bt[c4*4+3][row] = v.w;
            }
            __syncthreads();
            #pragma unroll
            for (int dk = 0; dk < DK; ++dk) {
                float4 a  = *(const float4*)&A[dk][ty * 4];
                float4 b0 = *(const float4*)&Bt[dk][tx * 8];
                float4 b1 = *(const float4*)&Bt[dk][tx * 8 + 4];
                float av[4] = {a.x, a.y, a.z, a.w};
                float bv[8] = {b0.x, b0.y, b0.z, b0.w, b1.x, b1.y, b1.z, b1.w};
                #pragma unroll
                for (int pi = 0; pi < 4; ++pi)
                    #pragma unroll
                    for (int ci = 0; ci < 8; ++ci)
                        acc[pi][ci] = fmaf(av[pi], bv[ci], acc[pi][ci]);
            }
        }

        // chunk top-2 per point, butterfly over the 16 code-lanes
        #pragma unroll
        for (int pi = 0; pi < 4; ++pi) {
            float v1 = 1e30f, v2 = 1e30f; int i1 = 0, i2 = 1;
            #pragma unroll
            for (int ci = 0; ci < 8; ++ci) {
                int code = cc + tx * 8 + ci;
                float sv = cnorm[code] - 2.0f * acc[pi][ci];
                if (sv < v1)       { v2 = v1; i2 = i1; v1 = sv; i1 = code; }
                else if (sv < v2)  { v2 = sv; i2 = code; }
            }
            for (int m = 1; m < 16; m <<= 1) {
                float w1 = __shfl_xor(v1, m); int j1 = __shfl_xor(i1, m);
                float w2 = __shfl_xor(v2, m); int j2 = __shfl_xor(i2, m);
                merge_top2(v1, i1, v2, i2, w1, j1, w2, j2);
            }
            merge_top2(best1[pi], bi1[pi], best2[pi], bi2[pi], v1, i1, v2, i2);
        }
    }

    // publish top-2 candidates
    if (tx == 0) {
        #pragma unroll
        for (int pi = 0; pi < 4; ++pi) {
            s_i1[ty * 4 + pi] = bi1[pi];
            s_i2[ty * 4 + pi] = bi2[pi];
        }
    }
    __syncthreads();

    // fp64 refine: 256 tasks = 64 points x 2 candidates x 2 halves
    {
        const int p = tid >> 2, cand = (tid >> 1) & 1, half = tid & 1;
        const int k = cand ? s_i2[p] : s_i1[p];
        const float* rr = r_in + (size_t)(pbase + p) * DIM + half * 512;
        const float* cr = cb + (size_t)k * DIM + half * 512;
        double s = 0.0;
        for (int d = 0; d < 512; ++d) {
            double c = (double)cr[d];
            double r = (double)rr[d];
            s += c * (c - 2.0 * r);
        }
        s_ref[p][cand][half] = s;
    }
    __syncthreads();
    if (tid < BM) {
        const int p = tid;
        double sA = s_ref[p][0][0] + s_ref[p][0][1];
        double sB = s_ref[p][1][0] + s_ref[p][1][1];
        int iA = s_i1[p], iB = s_i2[p];
        int w = (sB < sA || (sB == sA && iB < iA)) ? iB : iA;
        s_w[p] = w;
        out_idx_f[pbase + p] = (float)w;
        ws_idx[pbase + p] = w;
    }
    __syncthreads();

    // residual update + commitment-loss partial (loss term = mean(new_residual^2))
    float lsum = 0.0f;
    for (int p = 0; p < BM; ++p) {
        const int w = s_w[p];
        const size_t off = (size_t)(pbase + p) * DIM + tid * 4;
        float4 rv = *(const float4*)&r_in[off];
        float4 cv = *(const float4*)&cb[(size_t)w * DIM + tid * 4];
        float4 rn;
        rn.x = rv.x - cv.x; rn.y = rv.y - cv.y; rn.z = rv.z - cv.z; rn.w = rv.w - cv.w;
        if (r_out) *(float4*)&r_out[off] = rn;
        lsum += rn.x*rn.x + rn.y*rn.y + rn.z*rn.z + rn.w*rn.w;
    }
    s_red[tid] = lsum;
    __syncthreads();
    for (int o = 128; o > 0; o >>= 1) { if (tid < o) s_red[tid] += s_red[tid+o]; __syncthreads(); }
    if (tid == 0) loss_partial[blockIdx.x] = s_red[0];
}

// ---------------- deterministic bucket sums (no atomics) ----------------
// 512 blocks (one per code). sums[k] = sum of src rows with idx==k (+ nk*cb[k] if addC).
#define SCHUNK 4096
__global__ __launch_bounds__(256) void sums_kernel(
        const int* __restrict__ idx, const float* __restrict__ src,
        const float* __restrict__ cb, int addC,
        float* __restrict__ sums_out, int* __restrict__ counts_out)
{
    __shared__ int s_idx[SCHUNK];
    __shared__ int s_list[SCHUNK];
    __shared__ int s_scan[256];
    const int k = blockIdx.x, tid = threadIdx.x;
    float4 acc = make_float4(0.f, 0.f, 0.f, 0.f);
    int nk = 0;
    for (int base = 0; base < NPTS; base += SCHUNK) {
        __syncthreads();
        for (int j = tid; j < SCHUNK; j += 256) s_idx[j] = idx[base + j];
        __syncthreads();
        int cnt = 0;
        const int S = SCHUNK / 256;   // 16
        #pragma unroll
        for (int j = 0; j < S; ++j) cnt += (s_idx[tid * S + j] == k);
        s_scan[tid] = cnt;
        __syncthreads();
        for (int off = 1; off < 256; off <<= 1) {
            int v = (tid >= off) ? s_scan[tid - off] : 0;
            __syncthreads();
            s_scan[tid] += v;
            __syncthreads();
        }
        const int total = s_scan[255];
        int pos = s_scan[tid] - cnt;
        for (int j = 0; j < S; ++j)
            if (s_idx[tid * S + j] == k) s_list[pos++] = base + tid * S + j;
        __syncthreads();
        for (int j = 0; j < total; ++j) {
            const int pid = s_list[j];
            float4 v = *(const float4*)&src[(size_t)pid * DIM + tid * 4];
            acc.x += v.x; acc.y += v.y; acc.z += v.z; acc.w += v.w;
        }
        nk += total;
    }
    if (addC) {   // src was post-update residual: add back nk * C[k]
        float4 c = *(const float4*)&cb[(size_t)k * DIM + tid * 4];
        float fn = (float)nk;
        acc.x += fn * c.x; acc.y += fn * c.y; acc.z += fn * c.z; acc.w += fn * c.w;
    }
    *(float4*)&sums_out[(size_t)k * DIM + tid * 4] = acc;
    if (tid == 0) counts_out[k] = nk;
}

// ---------------- z_q_st = z_e - r2 + C2[idx2] (in-place on zq/r2 buffer) ----------------
__global__ __launch_bounds__(256) void zq_kernel(const float* __restrict__ z_e,
                                                 const float* __restrict__ cb2,
                                                 const int* __restrict__ idx2,
                                                 float* __restrict__ zq) {
    const int total = NPTS * (DIM / 4);   // float4 count = 16777216
    for (int i = blockIdx.x * 256 + threadIdx.x; i < total; i += gridDim.x * 256) {
        const size_t e = (size_t)i * 4;
        const int p = (int)(e >> 10);
        const int d = (int)(e & 1023);
        const int w = idx2[p];
        float4 z = *(const float4*)&z_e[e];
        float4 r = *(const float4*)&zq[e];
        float4 c = *(const float4*)&cb2[(size_t)w * DIM + d];
        float4 o;
        o.x = z.x - r.x + c.x; o.y = z.y - r.y + c.y;
        o.z = z.z - r.z + c.z; o.w = z.w - r.w + c.w;
        *(float4*)&zq[e] = o;
    }
}

// ---------------- n[l] = sum_k (0.99*ema_cluster + 0.01*counts) ----------------
__global__ __launch_bounds__(512) void nsum_kernel(const float* __restrict__ ec,
                                                   const int* __restrict__ counts,
                                                   float* __restrict__ n_ws) {
    __shared__ float sd[512];
    const int l = blockIdx.x, tid = threadIdx.x;
    sd[tid] = 0.99f * ec[l * NCODE + tid] + 0.01f * (float)counts[l * NCODE + tid];
    __syncthreads();
    for (int o = 256; o > 0; o >>= 1) { if (tid < o) sd[tid] += sd[tid+o]; __syncthreads(); }
    if (tid == 0) n_ws[l] = sd[0];
}

// ---------------- new_codebooks = (0.99*ema_w + 0.01*sums) / cs_norm ----------------
__global__ __launch_bounds__(256) void newcb_kernel(const float* __restrict__ ema_w,
                                                    const float* __restrict__ sums,
                                                    const float* __restrict__ ec,
                                                    const int* __restrict__ counts,
                                                    const float* __restrict__ n_ws,
                                                    float* __restrict__ out_cb) {
    const int b = blockIdx.x;          // l*512 + k
    const int tid = threadIdx.x;
    const int l = b >> 9;
    const float cs = 0.99f * ec[b] + 0.01f * (float)counts[b];
    const float n = n_ws[l];
    const float csn = (cs + 1e-5f) / (n + 512.0f * 1e-5f) * n;
    const size_t off = (size_t)b * DIM + tid * 4;
    float4 w = *(const float4*)&ema_w[off];
    float4 s4 = *(const float4*)&sums[off];
    float4 o;
    o.x = (0.99f * w.x + 0.01f * s4.x) / csn;
    o.y = (0.99f * w.y + 0.01f * s4.y) / csn;
    o.z = (0.99f * w.z + 0.01f * s4.z) / csn;
    o.w = (0.99f * w.w + 0.01f * s4.w) / csn;
    *(float4*)&out_cb[off] = o;
}

// ---------------- loss scalar ----------------
__global__ __launch_bounds__(256) void loss_kernel(const float* __restrict__ lp,
                                                   float* __restrict__ out_loss) {
    __shared__ double sd[256];
    const int tid = threadIdx.x;
    const double commit[3] = {0.25, 0.5, 1.0};
    double acc = 0.0;
    for (int l = 0; l < NLVL; ++l) {
        double s = 0.0;
        for (int j = tid; j < 1024; j += 256) s += (double)lp[l * 1024 + j];
        sd[tid] = s;
        __syncthreads();
        for (int o = 128; o > 0; o >>= 1) { if (tid < o) sd[tid] += sd[tid+o]; __syncthreads(); }
        if (tid == 0) acc += commit[l] * sd[0] / 67108864.0;
        __syncthreads();
    }
    if (tid == 0) *out_loss = (float)acc;
}

// ---------------- launcher ----------------
extern "C" void kernel_launch(void* const* d_in, const int* in_sizes, int n_in,
                              void* d_out, int out_size, void* d_ws, size_t ws_size,
                              hipStream_t stream) {
    const float* z_e   = (const float*)d_in[0];   // [16,4096,1024]
    const float* cbs   = (const float*)d_in[1];   // [3,512,1024]
    const float* ema_c = (const float*)d_in[2];   // [3,512]
    const float* ema_w = (const float*)d_in[3];   // [3,512,1024]
    float* out = (float*)d_out;

    char* ws = (char*)d_ws;
    int*   ws_idx = (int*)ws;                      // 3*65536 ints      (786432 B)
    float* cnorm  = (float*)(ws + 786432);         // 1536 floats
    int*   counts = (int*)(ws + 792576);           // 1536 ints
    float* lossp  = (float*)(ws + 798720);         // 3*1024 floats
    float* n_ws   = (float*)(ws + 811008);         // 3 floats (pad to 16)
    float* sums   = (float*)(ws + 811024);         // 3*512*1024 floats (~6 MB)

    float* zq       = out + ZQ_OFF;     // doubles as residual buffer
    float* out_loss = out + LOSS_OFF;
    float* out_idx  = out + IDX_OFF;
    float* out_cb   = out + CB_OFF;

    const float* cb0 = cbs;
    const float* cb1 = cbs + (size_t)1 * NCODE * DIM;
    const float* cb2 = cbs + (size_t)2 * NCODE * DIM;

    cnorm_kernel<<<NLVL * NCODE, 256, 0, stream>>>(cbs, cnorm);

    // level 0: r_in = z_e, r1 -> zq buffer
    level_kernel<<<NPTS / BM, NTHR, 0, stream>>>(z_e, zq, cb0, cnorm,
                                                 out_idx, ws_idx, lossp);
    // sums_0 over pre-residual = z_e (still intact)
    sums_kernel<<<NCODE, 256, 0, stream>>>(ws_idx, z_e, nullptr, 0,
                                           sums, counts);
    // level 1: in-place r1 -> r2 in zq buffer
    level_kernel<<<NPTS / BM, NTHR, 0, stream>>>(zq, zq, cb1, cnorm + NCODE,
                                                 out_idx + NPTS, ws_idx + NPTS, lossp + 1024);
    // sums_1 via post-residual trick: sum(r2 in bucket) + nk*C1[k]
    sums_kernel<<<NCODE, 256, 0, stream>>>(ws_idx + NPTS, zq, cb1, 1,
                                           sums + (size_t)NCODE * DIM, counts + NCODE);
    // level 2: r_in = r2 (kept intact), residual only in registers
    level_kernel<<<NPTS / BM, NTHR, 0, stream>>>(zq, nullptr, cb2, cnorm + 2 * NCODE,
                                                 out_idx + 2 * NPTS, ws_idx + 2 * NPTS, lossp + 2048);
    // sums_2 over pre-residual = r2 (still intact in zq buffer)
    sums_kernel<<<NCODE, 256, 0, stream>>>(ws_idx + 2 * NPTS, zq, nullptr, 0,
                                           sums + (size_t)2 * NCODE * DIM, counts + 2 * NCODE);
    // z_q_st = z_e - r2 + C2[idx2], in-place overwrite of zq buffer
    zq_kernel<<<4096, 256, 0, stream>>>(z_e, cb2, ws_idx + 2 * NPTS, zq);

    nsum_kernel<<<NLVL, 512, 0, stream>>>(ema_c, counts, n_ws);
    newcb_kernel<<<NLVL * NCODE, 256, 0, stream>>>(ema_w, sums, ema_c, counts, n_ws, out_cb);
    loss_kernel<<<1, 256, 0, stream>>>(lossp, out_loss);
}